// Round 1
// baseline (170.144 us; speedup 1.0000x reference)
//
#include <hip/hip_runtime.h>

#define EPS 1e-6f

// One block (256 threads) per row. Row is loaded once into registers as
// float4 (16 B/lane coalesced), sumsq reduced wave-wide via shfl_xor then
// across the 4 waves via 4-float LDS, then scaled and stored — single pass
// over HBM in each direction.
template <int VEC_PER_THREAD, int D>
__global__ __launch_bounds__(256) void rmsnorm_rows(const float* __restrict__ x,
                                                    const float* __restrict__ w,
                                                    float* __restrict__ out) {
    const int row = blockIdx.x;
    const float4* __restrict__ xr =
        reinterpret_cast<const float4*>(x + (size_t)row * D);
    float4* __restrict__ orow = reinterpret_cast<float4*>(out + (size_t)row * D);
    const float4* __restrict__ wv = reinterpret_cast<const float4*>(w);

    const int t = threadIdx.x;

    float4 v[VEC_PER_THREAD];
    float s = 0.f;
#pragma unroll
    for (int j = 0; j < VEC_PER_THREAD; ++j) {
        v[j] = xr[t + j * 256];
        s += v[j].x * v[j].x + v[j].y * v[j].y + v[j].z * v[j].z + v[j].w * v[j].w;
    }

    // Wave-64 butterfly reduction.
#pragma unroll
    for (int off = 32; off; off >>= 1) s += __shfl_xor(s, off);

    // Cross-wave (4 waves) reduction via LDS.
    __shared__ float red[4];
    const int wid = t >> 6;
    if ((t & 63) == 0) red[wid] = s;
    __syncthreads();
    s = red[0] + red[1] + red[2] + red[3];

    const float inv = rsqrtf(s * (1.0f / (float)D) + EPS);

#pragma unroll
    for (int j = 0; j < VEC_PER_THREAD; ++j) {
        const float4 wj = wv[t + j * 256];
        float4 o;
        o.x = v[j].x * inv * wj.x;
        o.y = v[j].y * inv * wj.y;
        o.z = v[j].z * inv * wj.z;
        o.w = v[j].w * inv * wj.w;
        orow[t + j * 256] = o;
    }
}

extern "C" void kernel_launch(void* const* d_in, const int* in_sizes, int n_in,
                              void* d_out, int out_size, void* d_ws, size_t ws_size,
                              hipStream_t stream) {
    (void)in_sizes; (void)n_in; (void)d_ws; (void)ws_size; (void)out_size;

    constexpr int B = 16384;
    constexpr int D1 = 6144;
    constexpr int D2 = 1024;

    const float* q = (const float*)d_in[0];
    const float* k = (const float*)d_in[1];
    const float* qw = (const float*)d_in[2];
    const float* kw = (const float*)d_in[3];

    float* out_q = (float*)d_out;
    float* out_k = out_q + (size_t)B * D1;

    rmsnorm_rows<D1 / (4 * 256), D1><<<B, 256, 0, stream>>>(q, qw, out_q);
    rmsnorm_rows<D2 / (4 * 256), D2><<<B, 256, 0, stream>>>(k, kw, out_k);
}

// Round 2
// 157.277 us; speedup vs baseline: 1.0818x; 1.0818x over previous
//
#include <hip/hip_runtime.h>

#define EPS 1e-6f

typedef float v4f __attribute__((ext_vector_type(4)));

__device__ __forceinline__ float dot4(v4f a) {
    return a.x * a.x + a.y * a.y + a.z * a.z + a.w * a.w;
}

__device__ __forceinline__ float wave_reduce(float s) {
#pragma unroll
    for (int off = 32; off; off >>= 1) s += __shfl_xor(s, off);
    return s;
}

// Fused: blocks [0, B) handle one q row each (256 thr, 6 v4f/thread).
// Blocks [B, B + B/4) handle 4 k rows each, one row per wave (4 v4f/lane,
// wave-only reduction, no barrier). Streaming data uses nontemporal
// loads/stores so L2/L3 stay available for the weight vectors.
template <int B, int D1, int D2>
__global__ __launch_bounds__(256) void qk_rmsnorm(const float* __restrict__ q,
                                                  const float* __restrict__ k,
                                                  const float* __restrict__ qw,
                                                  const float* __restrict__ kw,
                                                  float* __restrict__ oq,
                                                  float* __restrict__ ok) {
    const int b = blockIdx.x;
    const int t = threadIdx.x;

    if (b < B) {
        // ---- q row ----
        constexpr int VEC = D1 / (4 * 256);  // 6
        const v4f* __restrict__ xr = reinterpret_cast<const v4f*>(q + (size_t)b * D1);
        v4f* __restrict__ orow = reinterpret_cast<v4f*>(oq + (size_t)b * D1);
        const v4f* __restrict__ wv = reinterpret_cast<const v4f*>(qw);

        v4f v[VEC];
        float s = 0.f;
#pragma unroll
        for (int j = 0; j < VEC; ++j) {
            v[j] = __builtin_nontemporal_load(&xr[t + j * 256]);
            s += dot4(v[j]);
        }
        s = wave_reduce(s);

        __shared__ float red[4];
        const int wid = t >> 6;
        if ((t & 63) == 0) red[wid] = s;
        __syncthreads();
        s = red[0] + red[1] + red[2] + red[3];

        const float inv = rsqrtf(s * (1.0f / (float)D1) + EPS);

#pragma unroll
        for (int j = 0; j < VEC; ++j) {
            const v4f wj = wv[t + j * 256];
            __builtin_nontemporal_store(v[j] * inv * wj, &orow[t + j * 256]);
        }
    } else {
        // ---- 4 k rows, one per wave ----
        constexpr int VEC = D2 / (4 * 64);  // 4
        const int wid = t >> 6;
        const int lane = t & 63;
        const int row = (b - B) * 4 + wid;

        const v4f* __restrict__ xr = reinterpret_cast<const v4f*>(k + (size_t)row * D2);
        v4f* __restrict__ orow = reinterpret_cast<v4f*>(ok + (size_t)row * D2);
        const v4f* __restrict__ wv = reinterpret_cast<const v4f*>(kw);

        v4f v[VEC];
        float s = 0.f;
#pragma unroll
        for (int j = 0; j < VEC; ++j) {
            v[j] = __builtin_nontemporal_load(&xr[lane + j * 64]);
            s += dot4(v[j]);
        }
        s = wave_reduce(s);

        const float inv = rsqrtf(s * (1.0f / (float)D2) + EPS);

#pragma unroll
        for (int j = 0; j < VEC; ++j) {
            const v4f wj = wv[lane + j * 64];
            __builtin_nontemporal_store(v[j] * inv * wj, &orow[lane + j * 64]);
        }
    }
}

extern "C" void kernel_launch(void* const* d_in, const int* in_sizes, int n_in,
                              void* d_out, int out_size, void* d_ws, size_t ws_size,
                              hipStream_t stream) {
    (void)in_sizes; (void)n_in; (void)d_ws; (void)ws_size; (void)out_size;

    constexpr int B = 16384;
    constexpr int D1 = 6144;
    constexpr int D2 = 1024;

    const float* q = (const float*)d_in[0];
    const float* k = (const float*)d_in[1];
    const float* qw = (const float*)d_in[2];
    const float* kw = (const float*)d_in[3];

    float* out_q = (float*)d_out;
    float* out_k = out_q + (size_t)B * D1;

    qk_rmsnorm<B, D1, D2><<<B + B / 4, 256, 0, stream>>>(q, k, qw, kw, out_q, out_k);
}